// Round 5
// baseline (5005.529 us; speedup 1.0000x reference)
//
#include <hip/hip_runtime.h>
#include <math.h>

#define B_ 64
#define T_ 2048
#define E_ 128
#define H_ 128
#define G3_ 384   // 3*H
#define C_ 32
#define M_ (T_ * B_)   // 131072 tokens

typedef _Float16 f16x2 __attribute__((ext_vector_type(2)));
typedef _Float16 f16x4v __attribute__((ext_vector_type(4)));
typedef _Float16 f16x8 __attribute__((ext_vector_type(8)));
typedef float f32x4 __attribute__((ext_vector_type(4)));

__device__ __forceinline__ f16x2 as_h2(unsigned int u) {
    union { unsigned int u; f16x2 h; } c; c.u = u; return c.h;
}

#if __has_builtin(__builtin_amdgcn_fdot2)
__device__ __forceinline__ float fdot2_acc(f16x2 a, f16x2 b, float c) {
    return __builtin_amdgcn_fdot2(a, b, c, false);
}
#else
__device__ __forceinline__ float fdot2_acc(f16x2 a, f16x2 b, float c) {
    return fmaf((float)a.y, (float)b.y, fmaf((float)a.x, (float)b.x, c));
}
#endif

// ---------------------------------------------------------------------------
// K1/K3: gi[m][r] = bias[r] + dot(w[r][:], row_m[:]) ; m = t*B + b
// 384 threads, one output row per thread (64 weight VGPRs).
// ---------------------------------------------------------------------------
template <bool GATHER>
__global__ __launch_bounds__(384, 1) void gates_gemm(
    const float* __restrict__ src,   // emb [V,128] or y [M,128]
    const int*   __restrict__ xidx,  // x [B,T] or nullptr
    const float* __restrict__ w,     // [384,128]
    const float* __restrict__ bias,  // [384]
    float* __restrict__ gi)          // [M,384]
{
    const int r = threadIdx.x;  // output row 0..383
    f16x2 wr[64];
    {
        const float2* w2 = (const float2*)(w + (long)r * 128);
#pragma unroll
        for (int i = 0; i < 64; i++) {
            float2 v = w2[i];
            wr[i] = (f16x2){(_Float16)v.x, (_Float16)v.y};
        }
    }
    const float br = bias[r];

    __shared__ __align__(16) f16x2 rows[8][64];   // 8 tokens x 128 f16

    for (int grp = blockIdx.x; grp < M_ / 8; grp += gridDim.x) {
        const int m0 = grp * 8;
        __syncthreads();  // protect rows[] from readers of previous iter
        for (int j = r; j < 512; j += 384) {
            const int s = j >> 6;               // token in group
            const int p = j & 63;               // f16x2 pair within row
            const int mm = m0 + s;
            long row;
            if (GATHER) {
                const int t = mm >> 6;          // m = t*B + b, B=64
                const int bb = mm & 63;
                row = (long)xidx[bb * T_ + t];
            } else {
                row = mm;
            }
            float2 v = ((const float2*)(src + row * 128))[p];
            rows[s][p] = (f16x2){(_Float16)v.x, (_Float16)v.y};
        }
        __syncthreads();
        for (int s = 0; s < 8; s++) {
            const uint4* h16 = (const uint4*)rows[s];
            float a0 = br, a1 = 0.f, a2 = 0.f, a3 = 0.f;
#pragma unroll
            for (int i = 0; i < 16; i++) {
                uint4 u = h16[i];
                a0 = fdot2_acc(wr[4*i+0], as_h2(u.x), a0);
                a1 = fdot2_acc(wr[4*i+1], as_h2(u.y), a1);
                a2 = fdot2_acc(wr[4*i+2], as_h2(u.z), a2);
                a3 = fdot2_acc(wr[4*i+3], as_h2(u.w), a3);
            }
            gi[(long)(m0 + s) * G3_ + r] = (a0 + a1) + (a2 + a3);
        }
    }
}

// ---------------------------------------------------------------------------
// K2/K4: GRU recurrence — MFMA restructure.
// 4 workgroups x 512 threads (8 waves). WG handles 16 batch elements.
// Per step: gh[384x16] = W_hh[384x128] x h[128x16] via mfma_f32_16x16x32_f16.
// Wave q owns output rows {q*16..q*16+15} of each gate block (r,z,n) ->
// 3 tiles x 4 k-slices = 12 MFMA/wave/step. A-frags (weights) stationary in
// 48 VGPRs. h tile in LDS [b][k] f16, XOR-swizzled (^((b&7)<<4)), double-
// buffered; write-other-buffer -> ONE raw s_barrier per step, lgkmcnt-only
// drain (gi prefetch + y stores stay in flight across it). gi prefetched
// 2 steps ahead.
// Fragment maps (16x16x32): A: row=l&15,k=8*(l>>4)+j ; B: col=l&15, same k;
// D: col=l&15 (batch), row=4*(l>>4)+reg (h) — D verified (learn_hip m89).
// ---------------------------------------------------------------------------
#define GMFMA(ACC, AOP, BOP) \
    ACC = __builtin_amdgcn_mfma_f32_16x16x32_f16((AOP), (BOP), ACC, 0, 0, 0);

#define GSTEP(CUR, NXT, G0, G1, G2, TT, TP)                                    \
  {                                                                            \
    const char* hbuf = Hl[CUR];                                                \
    f16x8 bf0 = *(const f16x8*)(hbuf + rd0);                                   \
    f16x8 bf1 = *(const f16x8*)(hbuf + rd1);                                   \
    f16x8 bf2 = *(const f16x8*)(hbuf + rd2);                                   \
    f16x8 bf3 = *(const f16x8*)(hbuf + rd3);                                   \
    const int tp = ((TP) < T_) ? (TP) : (TT);                                  \
    const float* gp = gi + ((size_t)tp * B_ + bg) * G3_ + hb4;                 \
    const f32x4 nv0 = *(const f32x4*)(gp);                                     \
    const f32x4 nv1 = *(const f32x4*)(gp + 128);                               \
    const f32x4 nv2 = *(const f32x4*)(gp + 256);                               \
    f32x4 accR = Z4, accZ = Z4, accN = Z4;                                     \
    GMFMA(accR, aF[0][0], bf0) GMFMA(accZ, aF[1][0], bf0) GMFMA(accN, aF[2][0], bf0) \
    GMFMA(accR, aF[0][1], bf1) GMFMA(accZ, aF[1][1], bf1) GMFMA(accN, aF[2][1], bf1) \
    GMFMA(accR, aF[0][2], bf2) GMFMA(accZ, aF[1][2], bf2) GMFMA(accN, aF[2][2], bf2) \
    GMFMA(accR, aF[0][3], bf3) GMFMA(accZ, aF[1][3], bf3) GMFMA(accN, aF[2][3], bf3) \
    f16x4v hw;                                                                 \
    f32x4 yv;                                                                  \
    _Pragma("unroll")                                                          \
    for (int j = 0; j < 4; j++) {                                              \
      const float hr = accR[j] + bh0[j];                                       \
      const float hz = accZ[j] + bh1[j];                                       \
      const float hn = accN[j] + bh2[j];                                       \
      const float rr = 1.f / (1.f + __expf(-((G0)[j] + hr)));                  \
      const float zz = 1.f / (1.f + __expf(-((G1)[j] + hz)));                  \
      const float na = (G2)[j] + rr * hn;                                      \
      const float nn = 1.f - 2.f / (__expf(2.f * na) + 1.f);                   \
      const float hv = (1.f - zz) * nn + zz * hprev[j];                        \
      hprev[j] = hv; hw[j] = (_Float16)hv; yv[j] = hv;                         \
    }                                                                          \
    *(f16x4v*)(Hl[NXT] + wroff) = hw;                                          \
    *(f32x4*)(y + ((size_t)(TT) * B_ + bg) * H_ + hb4) = yv;                   \
    G0 = nv0; G1 = nv1; G2 = nv2;                                              \
    asm volatile("s_waitcnt lgkmcnt(0)" ::: "memory");                         \
    __builtin_amdgcn_s_barrier();                                              \
    __builtin_amdgcn_sched_barrier(0);                                         \
  }

__global__ __launch_bounds__(512, 2) void gru_layer(
    const float* __restrict__ gi,    // [M,384]
    const float* __restrict__ w_hh,  // [384,128]
    const float* __restrict__ b_hh,  // [384]
    float* __restrict__ y)           // [M,128]
{
    const int tid = threadIdx.x;
    const int q  = tid >> 6;         // wave id 0..7 -> output h-block
    const int l  = tid & 63;
    const int rl = l & 15;           // A row / B col / D col within tile
    const int kg = l >> 4;           // 0..3
    const int bg = blockIdx.x * 16 + rl;       // global batch (D col)
    const int hb4 = q * 16 + kg * 4;           // first h-dim of this lane's D rows

    // A-fragments: W_hh[G*128 + q*16 + rl][ks*32 + kg*8 + 0..7], fp32 -> f16
    f16x8 aF[3][4];
#pragma unroll
    for (int G = 0; G < 3; G++) {
        const float* wrow = w_hh + (size_t)(G * 128 + q * 16 + rl) * 128 + kg * 8;
#pragma unroll
        for (int ks = 0; ks < 4; ks++) {
            const f32x4 lo = *(const f32x4*)(wrow + ks * 32);
            const f32x4 hi = *(const f32x4*)(wrow + ks * 32 + 4);
            aF[G][ks] = (f16x8){(_Float16)lo[0], (_Float16)lo[1], (_Float16)lo[2], (_Float16)lo[3],
                                (_Float16)hi[0], (_Float16)hi[1], (_Float16)hi[2], (_Float16)hi[3]};
        }
    }
    const f32x4 bh0 = *(const f32x4*)(b_hh + 0   + hb4);
    const f32x4 bh1 = *(const f32x4*)(b_hh + 128 + hb4);
    const f32x4 bh2 = *(const f32x4*)(b_hh + 256 + hb4);

    // h tile: [buf][b][k] f16, byte addr = b*256 + k*2, XOR-swizzled by ((b&7)<<4)
    __shared__ __align__(16) char Hl[2][4096];

    if (tid < 256) *(f32x4*)(Hl[0] + tid * 16) = (f32x4){0.f, 0.f, 0.f, 0.f};

    // per-lane LDS byte offsets (16B-aligned reads, 8B-aligned write)
    const int swz = (rl & 7) << 4;
    const int rd0 = ((rl * 256 + (0 * 32 + kg * 8) * 2) ^ swz);
    const int rd1 = ((rl * 256 + (1 * 32 + kg * 8) * 2) ^ swz);
    const int rd2 = ((rl * 256 + (2 * 32 + kg * 8) * 2) ^ swz);
    const int rd3 = ((rl * 256 + (3 * 32 + kg * 8) * 2) ^ swz);
    const int wroff = ((rl * 256 + hb4 * 2) ^ swz);

    float hprev[4] = {0.f, 0.f, 0.f, 0.f};
    const f32x4 Z4 = {0.f, 0.f, 0.f, 0.f};

    // gi prefetch for t=0 and t=1
    const float* g0p = gi + ((size_t)0 * B_ + bg) * G3_ + hb4;
    const float* g1p = gi + ((size_t)1 * B_ + bg) * G3_ + hb4;
    f32x4 gA0 = *(const f32x4*)(g0p);
    f32x4 gA1 = *(const f32x4*)(g0p + 128);
    f32x4 gA2 = *(const f32x4*)(g0p + 256);
    f32x4 gB0 = *(const f32x4*)(g1p);
    f32x4 gB1 = *(const f32x4*)(g1p + 128);
    f32x4 gB2 = *(const f32x4*)(g1p + 256);

    __syncthreads();  // one-time full drain: buf0 zero-init visible

    for (int t = 0; t < T_; t += 2) {
        GSTEP(0, 1, gA0, gA1, gA2, t,     t + 2)
        GSTEP(1, 0, gB0, gB1, gB2, t + 1, t + 3)
    }
}

// ---------------------------------------------------------------------------
// K5: out[b*T+t][c] = relu(fc_b[c] + dot(fc_w[c], y[t*B+b]))
// ---------------------------------------------------------------------------
__global__ __launch_bounds__(256, 2) void fc_relu(
    const float* __restrict__ y,     // [M,128]
    const float* __restrict__ fc_w,  // [32,128]
    const float* __restrict__ fc_b,  // [32]
    float* __restrict__ out)         // [B*T,32]
{
    const int tid = threadIdx.x;
    const int c = tid & 31;
    const int slot = tid >> 5;

    float4 wr[32];
    const float4* w4 = (const float4*)(fc_w + c * 128);
#pragma unroll
    for (int i = 0; i < 32; i++) wr[i] = w4[i];
    const float bc = fc_b[c];

    __shared__ __align__(16) float rows[8][128];

    for (int grp = blockIdx.x; grp < M_ / 8; grp += gridDim.x) {
        const int m0 = grp * 8;
        __syncthreads();
        for (int i = tid; i < 8 * 128; i += 256) {
            rows[i >> 7][i & 127] = y[(long)m0 * 128 + i];
        }
        __syncthreads();
        const float4* h4 = (const float4*)rows[slot];
        float a0 = bc, a1 = 0.f, a2 = 0.f, a3 = 0.f;
#pragma unroll
        for (int i = 0; i < 32; i += 4) {
            float4 h0 = h4[i], h1 = h4[i + 1], h2 = h4[i + 2], h3 = h4[i + 3];
            a0 = fmaf(wr[i].w, h0.w, fmaf(wr[i].z, h0.z, fmaf(wr[i].y, h0.y, fmaf(wr[i].x, h0.x, a0))));
            a1 = fmaf(wr[i+1].w, h1.w, fmaf(wr[i+1].z, h1.z, fmaf(wr[i+1].y, h1.y, fmaf(wr[i+1].x, h1.x, a1))));
            a2 = fmaf(wr[i+2].w, h2.w, fmaf(wr[i+2].z, h2.z, fmaf(wr[i+2].y, h2.y, fmaf(wr[i+2].x, h2.x, a2))));
            a3 = fmaf(wr[i+3].w, h3.w, fmaf(wr[i+3].z, h3.z, fmaf(wr[i+3].y, h3.y, fmaf(wr[i+3].x, h3.x, a3))));
        }
        float acc = (a0 + a1) + (a2 + a3);
        acc = fmaxf(acc, 0.f);
        const int m = m0 + slot;
        const int t = m >> 6;
        const int b = m & 63;
        out[((long)b * T_ + t) * C_ + c] = acc;
    }
}

// ---------------------------------------------------------------------------
extern "C" void kernel_launch(void* const* d_in, const int* in_sizes, int n_in,
                              void* d_out, int out_size, void* d_ws, size_t ws_size,
                              hipStream_t stream) {
    const int*   x     = (const int*)d_in[0];
    const float* emb   = (const float*)d_in[1];
    const float* w_ih0 = (const float*)d_in[2];
    const float* w_hh0 = (const float*)d_in[3];
    const float* b_ih0 = (const float*)d_in[4];
    const float* b_hh0 = (const float*)d_in[5];
    const float* w_ih1 = (const float*)d_in[6];
    const float* w_hh1 = (const float*)d_in[7];
    const float* b_ih1 = (const float*)d_in[8];
    const float* b_hh1 = (const float*)d_in[9];
    const float* fc_w  = (const float*)d_in[10];
    const float* fc_b  = (const float*)d_in[11];
    float* out = (float*)d_out;

    // workspace: gi [M,384] fp32 (201.3 MB, reused for both layers) + y [M,128] (67.1 MB)
    float* gi = (float*)d_ws;
    float* yb = (float*)((char*)d_ws + (size_t)M_ * G3_ * sizeof(float));

    // layer 0 input gates (embedding gather fused)
    gates_gemm<true><<<512, 384, 0, stream>>>(emb, x, w_ih0, b_ih0, gi);
    // layer 0 recurrence (MFMA, 4 WGs x 16 batches)
    gru_layer<<<4, 512, 0, stream>>>(gi, w_hh0, b_hh0, yb);
    // layer 1 input gates
    gates_gemm<false><<<512, 384, 0, stream>>>(yb, nullptr, w_ih1, b_ih1, gi);
    // layer 1 recurrence
    gru_layer<<<4, 512, 0, stream>>>(gi, w_hh1, b_hh1, yb);
    // FC + ReLU
    fc_relu<<<512, 256, 0, stream>>>(yb, fc_w, fc_b, out);
}